// Round 3
// baseline (209.206 us; speedup 1.0000x reference)
//
#include <hip/hip_runtime.h>

typedef __bf16 bf16_t;
typedef __bf16 bf16x4 __attribute__((ext_vector_type(4)));
typedef __bf16 bf16x8 __attribute__((ext_vector_type(8)));
typedef float f32x4 __attribute__((ext_vector_type(4)));

#define T_SEQ 1024
#define EMB   512
#define NH    8
#define HD    64
#define BATCH 2
#define NBH   (BATCH*NH)      // 16
#define CHUNK 64
#define NCHUNK (T_SEQ/CHUNK)  // 16
#define NBLK  (NBH*NCHUNK)    // 256

// Identity used throughout: with ang_t = (pi/2)*t/T,
//   q_cos[t].k_cos[s] + q_sin[t].k_sin[s] = (q'[t].k'[s]) * cos(ang_t - ang_s)
// so we store only raw relu'd q', k' and apply weights on the fly.

// ---------------------------------------------------------------------------
// K0: fp32 -> bf16 convert (inputs are float32 per the reference).
// ---------------------------------------------------------------------------
__global__ __launch_bounds__(256) void cvt_kernel(
    const float* __restrict__ src, bf16_t* __restrict__ dst, int n4)
{
    int i = blockIdx.x * 256 + threadIdx.x;
    if (i < n4) {
        float4 v = ((const float4*)src)[i];
        bf16x4 o;
        o[0] = (bf16_t)v.x; o[1] = (bf16_t)v.y;
        o[2] = (bf16_t)v.z; o[3] = (bf16_t)v.w;
        ((bf16x4*)dst)[i] = o;
    }
}

// ---------------------------------------------------------------------------
// K1: qkv = x @ w_qkv^T + b_qkv, fused relu + head-layout scatter.
// MFMA 16x16x32 bf16, one wave per 16x16 C tile (NT layout).
// A-frag: lane holds A[m0+(lane&15)][k0+(lane>>4)*8+j], j=0..7
// C/D:    col = lane&15 (n), row = (lane>>4)*4 + reg   [guide §3, m89]
// ---------------------------------------------------------------------------
__global__ __launch_bounds__(256) void qkv_gemm_kernel(
    const bf16_t* __restrict__ X, const bf16_t* __restrict__ W,
    const float* __restrict__ bias,
    bf16_t* __restrict__ qq, bf16_t* __restrict__ kk, bf16_t* __restrict__ vv)
{
    const int wave = threadIdx.x >> 6;
    const int lane = threadIdx.x & 63;
    const int m0 = blockIdx.x * 16;
    const int n0 = blockIdx.y * 64 + wave * 16;
    const int rsel = lane & 15;
    const int koff = (lane >> 4) * 8;
    f32x4 acc = {0.f, 0.f, 0.f, 0.f};
    const bf16_t* Ap = X + (m0 + rsel) * EMB + koff;
    const bf16_t* Bp = W + (n0 + rsel) * EMB + koff;
    for (int k0 = 0; k0 < EMB; k0 += 32) {
        bf16x8 af = *reinterpret_cast<const bf16x8*>(Ap + k0);
        bf16x8 bfv = *reinterpret_cast<const bf16x8*>(Bp + k0);
        acc = __builtin_amdgcn_mfma_f32_16x16x32_bf16(af, bfv, acc, 0, 0, 0);
    }
    const int n = n0 + (lane & 15);
    const int mb = m0 + (lane >> 4) * 4;
    const float bn = bias[n];
    const int sec = n >> 9;          // 0=q 1=k 2=v
    const int c = n & 511;
    const int h = c >> 6, e = c & 63;
    for (int r = 0; r < 4; ++r) {
        int m = mb + r;
        int b = m >> 10, t = m & 1023;
        float val = acc[r] + bn;
        int di = ((b * NH + h) * T_SEQ + t) * HD + e;
        if (sec == 0) {
            qq[di] = (bf16_t)fmaxf(val, 0.f);
        } else if (sec == 1) {
            kk[di] = (bf16_t)fmaxf(val, 0.f);
        } else {
            vv[di] = (bf16_t)val;
        }
    }
}

// ---------------------------------------------------------------------------
// K2: per-chunk weighted sums:
//   Ssc[blk][i][j] = sum_t cw_t*k'[t][i]*v[t][j]   (bf16 out)
//   Sss[blk][i][j] = sum_t sw_t*k'[t][i]*v[t][j]
//   zc[blk][i]     = sum_t cw_t*k'[t][i]           (fp32 out)
// ---------------------------------------------------------------------------
__global__ __launch_bounds__(256) void chunk_sum_kernel(
    const bf16_t* __restrict__ kk, const bf16_t* __restrict__ vv,
    bf16_t* __restrict__ Ssc, bf16_t* __restrict__ Sss,
    float* __restrict__ zc, float* __restrict__ zs)
{
    const int blk = blockIdx.x;
    const int ch = blk & 15;
    __shared__ __align__(16) bf16_t sk[CHUNK * HD];
    __shared__ __align__(16) bf16_t sv[CHUNK * HD];
    __shared__ float cwt[CHUNK], swt[CHUNK];
    const int base = blk * CHUNK * HD;   // contiguous chunk in [bh][t][e]
    for (int i = threadIdx.x; i < CHUNK * HD / 8; i += 256) {
        ((uint4*)sk)[i] = ((const uint4*)(kk + base))[i];
        ((uint4*)sv)[i] = ((const uint4*)(vv + base))[i];
    }
    if (threadIdx.x < CHUNK) {
        int tg = ch * CHUNK + threadIdx.x;
        float ang = 1.5707963267948966f * (float)tg * (1.0f / (float)T_SEQ);
        cwt[threadIdx.x] = cosf(ang);
        swt[threadIdx.x] = sinf(ang);
    }
    __syncthreads();
    const int i  = threadIdx.x >> 2;        // k-dim index 0..63
    const int jg = (threadIdx.x & 3) * 16;  // v-dim group
    float ac[16], as[16];
    for (int jj = 0; jj < 16; ++jj) { ac[jj] = 0.f; as[jj] = 0.f; }
    for (int t = 0; t < CHUNK; ++t) {
        float kv = (float)sk[t * HD + i];
        float kc_ = kv * cwt[t];
        float ks_ = kv * swt[t];
        for (int jj = 0; jj < 16; ++jj) {
            float vj = (float)sv[t * HD + jg + jj];
            ac[jj] += kc_ * vj;
            as[jj] += ks_ * vj;
        }
    }
    bf16_t* oc = Ssc + blk * HD * HD;
    bf16_t* os = Sss + blk * HD * HD;
    for (int jj = 0; jj < 16; ++jj) {
        oc[i * HD + jg + jj] = (bf16_t)ac[jj];
        os[i * HD + jg + jj] = (bf16_t)as[jj];
    }
    if (threadIdx.x < HD) {
        int ii = threadIdx.x;
        float s = 0.f;
        for (int t = 0; t < CHUNK; ++t) s += (float)sk[t * HD + ii] * cwt[t];
        zc[blk * HD + ii] = s;
    } else if (threadIdx.x < 2 * HD) {
        int ii = threadIdx.x - HD;
        float s = 0.f;
        for (int t = 0; t < CHUNK; ++t) s += (float)sk[t * HD + ii] * swt[t];
        zs[blk * HD + ii] = s;
    }
}

// ---------------------------------------------------------------------------
// K3: in-place exclusive prefix scan over chunks per bh (16 chunks).
// S stored bf16, running sum kept fp32; z is fp32.
// ---------------------------------------------------------------------------
__global__ __launch_bounds__(256) void scan_kernel(
    bf16_t* __restrict__ Ssc, bf16_t* __restrict__ Sss,
    float* __restrict__ zc, float* __restrict__ zs)
{
    const int bh = blockIdx.x;
    for (int e = threadIdx.x; e < HD * HD; e += 256) {
        float r1 = 0.f, r2 = 0.f;
        for (int c = 0; c < NCHUNK; ++c) {
            int idx = (bh * NCHUNK + c) * HD * HD + e;
            float t1 = (float)Ssc[idx]; Ssc[idx] = (bf16_t)r1; r1 += t1;
            float t2 = (float)Sss[idx]; Sss[idx] = (bf16_t)r2; r2 += t2;
        }
    }
    if (threadIdx.x < HD) {
        int e = threadIdx.x;
        float r1 = 0.f, r2 = 0.f;
        for (int c = 0; c < NCHUNK; ++c) {
            int idx = (bh * NCHUNK + c) * HD + e;
            float t1 = zc[idx]; zc[idx] = r1; r1 += t1;
            float t2 = zs[idx]; zs[idx] = r2; r2 += t2;
        }
    }
}

// ---------------------------------------------------------------------------
// K4: per-chunk output.
//   P[t][s] = (q'[t].k'[s]) * cosd[t-s]  for s<=t else 0
//   ctx[t][e] = sum_{s<=t} P[t][s] v[s][e]
//             + sum_i q'[t][i] * (cw_t*Spc[i][e] + sw_t*Sps[i][e])
//   nrm[t]    = sum_{s<=t} P[t][s] + sum_i q'[t][i]*(cw_t*zc[i] + sw_t*zs[i])
//   Y[b, tg, h*64+e] = ctx/(nrm+eps)  ([B,T,E] bf16 layout for K5)
// ---------------------------------------------------------------------------
__global__ __launch_bounds__(256) void chunk_out_kernel(
    const bf16_t* __restrict__ qq, const bf16_t* __restrict__ kk,
    const bf16_t* __restrict__ vv,
    const bf16_t* __restrict__ Ssc, const bf16_t* __restrict__ Sss,
    const float* __restrict__ zc, const float* __restrict__ zs,
    bf16_t* __restrict__ Y)
{
    const int blk = blockIdx.x;
    const int bh = blk >> 4, ch = blk & 15;
    __shared__ __align__(16) bf16_t sq[CHUNK * HD];
    __shared__ __align__(16) bf16_t sk[CHUNK * HD];
    __shared__ __align__(16) bf16_t sv[CHUNK * HD];
    __shared__ float P[CHUNK * CHUNK];
    __shared__ float nrm[CHUNK];
    __shared__ float cwt[CHUNK], swt[CHUNK], cosd[CHUNK];
    const int base = blk * CHUNK * HD;
    for (int i = threadIdx.x; i < CHUNK * HD / 8; i += 256) {
        ((uint4*)sq)[i] = ((const uint4*)(qq + base))[i];
        ((uint4*)sk)[i] = ((const uint4*)(kk + base))[i];
        ((uint4*)sv)[i] = ((const uint4*)(vv + base))[i];
    }
    if (threadIdx.x < CHUNK) {
        int tl = threadIdx.x;
        int tg = ch * CHUNK + tl;
        float ang = 1.5707963267948966f * (float)tg * (1.0f / (float)T_SEQ);
        cwt[tl] = cosf(ang);
        swt[tl] = sinf(ang);
        cosd[tl] = cosf(1.5707963267948966f * (float)tl * (1.0f / (float)T_SEQ));
    }
    __syncthreads();
    const int t  = threadIdx.x >> 2;
    const int sg = (threadIdx.x & 3) * 16;
    for (int ss = 0; ss < 16; ++ss) {
        int s = sg + ss;
        float p = 0.f;
        if (s <= t) {
            float p0 = 0.f;
            for (int i = 0; i < HD; ++i)
                p0 += (float)sq[t * HD + i] * (float)sk[s * HD + i];
            p = p0 * cosd[t - s];
        }
        P[t * CHUNK + s] = p;
    }
    __syncthreads();
    float acc[16];
    for (int ee = 0; ee < 16; ++ee) acc[ee] = 0.f;
    const int eg = sg;
    for (int s = 0; s <= t; ++s) {
        float p = P[t * CHUNK + s];
        for (int ee = 0; ee < 16; ++ee)
            acc[ee] += p * (float)sv[s * HD + eg + ee];
    }
    const float cw = cwt[t], sw = swt[t];
    const bf16_t* Spc = Ssc + blk * HD * HD;
    const bf16_t* Sps = Sss + blk * HD * HD;
    for (int i = 0; i < HD; ++i) {
        float qi = (float)sq[t * HD + i];
        float qciw = qi * cw;
        float qsiw = qi * sw;
        const bf16x8* pc = (const bf16x8*)(Spc + i * HD + eg);
        const bf16x8* ps = (const bf16x8*)(Sps + i * HD + eg);
        bf16x8 c0 = pc[0], c1 = pc[1];
        bf16x8 s0 = ps[0], s1 = ps[1];
        for (int j = 0; j < 8; ++j) {
            acc[j]     += qciw * (float)c0[j] + qsiw * (float)s0[j];
            acc[8 + j] += qciw * (float)c1[j] + qsiw * (float)s1[j];
        }
    }
    if ((threadIdx.x & 3) == 0) {
        float nv = 0.f;
        for (int s = 0; s <= t; ++s) nv += P[t * CHUNK + s];
        const float* zcp = zc + blk * HD;
        const float* zsp = zs + blk * HD;
        for (int i = 0; i < HD; ++i) {
            float qi = (float)sq[t * HD + i];
            nv += qi * (cw * zcp[i] + sw * zsp[i]);
        }
        nrm[t] = nv;
    }
    __syncthreads();
    const float inv = 1.0f / (nrm[t] + 1e-6f);
    const int b = bh >> 3, h = bh & 7;
    const int tg = ch * CHUNK + t;
    bf16_t* Yp = Y + ((b * T_SEQ + tg) * EMB) + h * HD + eg;
    for (int ee = 0; ee < 16; ++ee) Yp[ee] = (bf16_t)(acc[ee] * inv);
}

// ---------------------------------------------------------------------------
// K5: out = Y @ w_out^T + b_out. fp32 output.
// ---------------------------------------------------------------------------
__global__ __launch_bounds__(256) void out_gemm_kernel(
    const bf16_t* __restrict__ Yb, const bf16_t* __restrict__ W,
    const float* __restrict__ bias, float* __restrict__ out)
{
    const int wave = threadIdx.x >> 6;
    const int lane = threadIdx.x & 63;
    const int m0 = blockIdx.x * 16;
    const int n0 = blockIdx.y * 64 + wave * 16;
    const int rsel = lane & 15;
    const int koff = (lane >> 4) * 8;
    f32x4 acc = {0.f, 0.f, 0.f, 0.f};
    const bf16_t* Ap = Yb + (m0 + rsel) * EMB + koff;
    const bf16_t* Bp = W + (n0 + rsel) * EMB + koff;
    for (int k0 = 0; k0 < EMB; k0 += 32) {
        bf16x8 af = *reinterpret_cast<const bf16x8*>(Ap + k0);
        bf16x8 bfv = *reinterpret_cast<const bf16x8*>(Bp + k0);
        acc = __builtin_amdgcn_mfma_f32_16x16x32_bf16(af, bfv, acc, 0, 0, 0);
    }
    const int n = n0 + (lane & 15);
    const int mb = m0 + (lane >> 4) * 4;
    const float bn = bias[n];
    for (int r = 0; r < 4; ++r) {
        int m = mb + r;
        out[m * EMB + n] = acc[r] + bn;
    }
}

extern "C" void kernel_launch(void* const* d_in, const int* in_sizes, int n_in,
                              void* d_out, int out_size, void* d_ws, size_t ws_size,
                              hipStream_t stream) {
    const float* x     = (const float*)d_in[0];   // [2,1024,512] fp32
    const float* w_qkv = (const float*)d_in[1];   // [1536,512] fp32
    const float* b_qkv = (const float*)d_in[2];   // [1536] fp32
    const float* w_out = (const float*)d_in[3];   // [512,512] fp32
    const float* b_out = (const float*)d_in[4];   // [512] fp32
    float* out = (float*)d_out;                   // [2,1024,512] fp32

    char* w = (char*)d_ws;
    const size_t N_X   = (size_t)BATCH * T_SEQ * EMB;   // 1,048,576
    const size_t N_WQ  = (size_t)3 * EMB * EMB;         //   786,432
    const size_t N_WO  = (size_t)EMB * EMB;             //   262,144
    bf16_t* xb   = (bf16_t*)w;                 w += N_X  * sizeof(bf16_t);
    bf16_t* wqb  = (bf16_t*)w;                 w += N_WQ * sizeof(bf16_t);
    bf16_t* wob  = (bf16_t*)w;                 w += N_WO * sizeof(bf16_t);
    const size_t SZ_BHTD = (size_t)NBH * T_SEQ * HD * sizeof(bf16_t); // 2 MB
    bf16_t* qq = (bf16_t*)w;                   w += SZ_BHTD;
    bf16_t* kk = (bf16_t*)w;                   w += SZ_BHTD;
    bf16_t* vv = (bf16_t*)w;                   w += SZ_BHTD;
    bf16_t* Y  = (bf16_t*)w;                   w += SZ_BHTD;
    bf16_t* Ssc = (bf16_t*)w;                  w += (size_t)NBLK * HD * HD * sizeof(bf16_t);
    bf16_t* Sss = (bf16_t*)w;                  w += (size_t)NBLK * HD * HD * sizeof(bf16_t);
    float* zc = (float*)w;                     w += (size_t)NBLK * HD * sizeof(float);
    float* zs = (float*)w;

    cvt_kernel<<<(int)(N_X / 4 + 255) / 256, 256, 0, stream>>>(x, xb, (int)(N_X / 4));
    cvt_kernel<<<(int)(N_WQ / 4 + 255) / 256, 256, 0, stream>>>(w_qkv, wqb, (int)(N_WQ / 4));
    cvt_kernel<<<(int)(N_WO / 4 + 255) / 256, 256, 0, stream>>>(w_out, wob, (int)(N_WO / 4));

    qkv_gemm_kernel<<<dim3(2048 / 16, 1536 / 64), 256, 0, stream>>>(
        xb, wqb, b_qkv, qq, kk, vv);
    chunk_sum_kernel<<<NBLK, 256, 0, stream>>>(kk, vv, Ssc, Sss, zc, zs);
    scan_kernel<<<NBH, 256, 0, stream>>>(Ssc, Sss, zc, zs);
    chunk_out_kernel<<<NBLK, 256, 0, stream>>>(qq, kk, vv, Ssc, Sss, zc, zs, Y);
    out_gemm_kernel<<<dim3(2048 / 16, 512 / 64), 256, 0, stream>>>(
        Y, wob, b_out, out);
}

// Round 4
// 170.860 us; speedup vs baseline: 1.2244x; 1.2244x over previous
//
#include <hip/hip_runtime.h>

typedef __bf16 bf16_t;
typedef __bf16 bf16x4 __attribute__((ext_vector_type(4)));
typedef __bf16 bf16x8 __attribute__((ext_vector_type(8)));
typedef float f32x4 __attribute__((ext_vector_type(4)));

#define T_SEQ 1024
#define EMB   512
#define NH    8
#define HD    64
#define BATCH 2
#define NBH   (BATCH*NH)      // 16
#define CHUNK 64
#define NCHUNK (T_SEQ/CHUNK)  // 16
#define NBLK  (NBH*NCHUNK)    // 256
#define LDA   72              // padded LDS row stride (9x8: keeps 16B align, spreads banks)

// Identity: with ang_t = (pi/2)*t/T,
//   q_cos[t].k_cos[s] + q_sin[t].k_sin[s] = (q'[t].k'[s]) * cos(ang_t - ang_s)

// ---------------------------------------------------------------------------
// K0: fp32 -> bf16 convert (inputs are float32 per the reference).
// ---------------------------------------------------------------------------
__global__ __launch_bounds__(256) void cvt_kernel(
    const float* __restrict__ src, bf16_t* __restrict__ dst, int n4)
{
    int i = blockIdx.x * 256 + threadIdx.x;
    if (i < n4) {
        float4 v = ((const float4*)src)[i];
        bf16x4 o;
        o[0] = (bf16_t)v.x; o[1] = (bf16_t)v.y;
        o[2] = (bf16_t)v.z; o[3] = (bf16_t)v.w;
        ((bf16x4*)dst)[i] = o;
    }
}

// ---------------------------------------------------------------------------
// K1: qkv = x @ w_qkv^T + b_qkv, fused relu + head-layout scatter.
// MFMA 16x16x32 bf16, one wave per 16x16 C tile (NT layout).
// ---------------------------------------------------------------------------
__global__ __launch_bounds__(256) void qkv_gemm_kernel(
    const bf16_t* __restrict__ X, const bf16_t* __restrict__ W,
    const float* __restrict__ bias,
    bf16_t* __restrict__ qq, bf16_t* __restrict__ kk, bf16_t* __restrict__ vv)
{
    const int wave = threadIdx.x >> 6;
    const int lane = threadIdx.x & 63;
    const int m0 = blockIdx.x * 16;
    const int n0 = blockIdx.y * 64 + wave * 16;
    const int rsel = lane & 15;
    const int koff = (lane >> 4) * 8;
    f32x4 acc = {0.f, 0.f, 0.f, 0.f};
    const bf16_t* Ap = X + (m0 + rsel) * EMB + koff;
    const bf16_t* Bp = W + (n0 + rsel) * EMB + koff;
    for (int k0 = 0; k0 < EMB; k0 += 32) {
        bf16x8 af = *reinterpret_cast<const bf16x8*>(Ap + k0);
        bf16x8 bfv = *reinterpret_cast<const bf16x8*>(Bp + k0);
        acc = __builtin_amdgcn_mfma_f32_16x16x32_bf16(af, bfv, acc, 0, 0, 0);
    }
    const int n = n0 + (lane & 15);
    const int mb = m0 + (lane >> 4) * 4;
    const float bn = bias[n];
    const int sec = n >> 9;          // 0=q 1=k 2=v
    const int c = n & 511;
    const int h = c >> 6, e = c & 63;
    for (int r = 0; r < 4; ++r) {
        int m = mb + r;
        int b = m >> 10, t = m & 1023;
        float val = acc[r] + bn;
        int di = ((b * NH + h) * T_SEQ + t) * HD + e;
        if (sec == 0) {
            qq[di] = (bf16_t)fmaxf(val, 0.f);
        } else if (sec == 1) {
            kk[di] = (bf16_t)fmaxf(val, 0.f);
        } else {
            vv[di] = (bf16_t)val;
        }
    }
}

// ---------------------------------------------------------------------------
// K2: per-chunk weighted sums, stored TRANSPOSED for K4's MFMA B-operand:
//   Ssc[blk][e][i] = sum_t cw_t*k'[t][i]*v[t][e]   (bf16, [e][i] layout!)
//   Sss[blk][e][i] = sum_t sw_t*k'[t][i]*v[t][e]
//   zc[blk][i]     = sum_t cw_t*k'[t][i]           (fp32)
// Thread map: i = tid&63 (coalesced in i), jg = (tid>>6)*16 over e.
// ---------------------------------------------------------------------------
__global__ __launch_bounds__(256) void chunk_sum_kernel(
    const bf16_t* __restrict__ kk, const bf16_t* __restrict__ vv,
    bf16_t* __restrict__ Ssc, bf16_t* __restrict__ Sss,
    float* __restrict__ zc, float* __restrict__ zs)
{
    const int blk = blockIdx.x;
    const int ch = blk & 15;
    __shared__ __align__(16) bf16_t sk[CHUNK * HD];
    __shared__ __align__(16) bf16_t sv[CHUNK * HD];
    __shared__ float cwt[CHUNK], swt[CHUNK];
    const int base = blk * CHUNK * HD;
    for (int i = threadIdx.x; i < CHUNK * HD / 8; i += 256) {
        ((uint4*)sk)[i] = ((const uint4*)(kk + base))[i];
        ((uint4*)sv)[i] = ((const uint4*)(vv + base))[i];
    }
    if (threadIdx.x < CHUNK) {
        int tg = ch * CHUNK + threadIdx.x;
        float ang = 1.5707963267948966f * (float)tg * (1.0f / (float)T_SEQ);
        cwt[threadIdx.x] = cosf(ang);
        swt[threadIdx.x] = sinf(ang);
    }
    __syncthreads();
    const int i  = threadIdx.x & 63;        // k'-feature index
    const int jg = (threadIdx.x >> 6) * 16; // v-feature (e) group
    float ac[16], as[16];
    for (int jj = 0; jj < 16; ++jj) { ac[jj] = 0.f; as[jj] = 0.f; }
    for (int t = 0; t < CHUNK; ++t) {
        float kv = (float)sk[t * HD + i];
        float kc_ = kv * cwt[t];
        float ks_ = kv * swt[t];
        for (int jj = 0; jj < 16; ++jj) {
            float vj = (float)sv[t * HD + jg + jj];
            ac[jj] += kc_ * vj;
            as[jj] += ks_ * vj;
        }
    }
    bf16_t* oc = Ssc + blk * HD * HD;
    bf16_t* os = Sss + blk * HD * HD;
    for (int jj = 0; jj < 16; ++jj) {
        oc[(jg + jj) * HD + i] = (bf16_t)ac[jj];   // transposed: [e][i]
        os[(jg + jj) * HD + i] = (bf16_t)as[jj];
    }
    if (threadIdx.x < HD) {
        int ii = threadIdx.x;
        float s = 0.f;
        for (int t = 0; t < CHUNK; ++t) s += (float)sk[t * HD + ii] * cwt[t];
        zc[blk * HD + ii] = s;
    } else if (threadIdx.x < 2 * HD) {
        int ii = threadIdx.x - HD;
        float s = 0.f;
        for (int t = 0; t < CHUNK; ++t) s += (float)sk[t * HD + ii] * swt[t];
        zs[blk * HD + ii] = s;
    }
}

// ---------------------------------------------------------------------------
// K3: in-place exclusive prefix scan over chunks per bh (16 chunks).
// Elementwise over the HD*HD block, so layout-agnostic.
// ---------------------------------------------------------------------------
__global__ __launch_bounds__(256) void scan_kernel(
    bf16_t* __restrict__ Ssc, bf16_t* __restrict__ Sss,
    float* __restrict__ zc, float* __restrict__ zs)
{
    const int bh = blockIdx.x;
    for (int e = threadIdx.x; e < HD * HD; e += 256) {
        float r1 = 0.f, r2 = 0.f;
        for (int c = 0; c < NCHUNK; ++c) {
            int idx = (bh * NCHUNK + c) * HD * HD + e;
            float t1 = (float)Ssc[idx]; Ssc[idx] = (bf16_t)r1; r1 += t1;
            float t2 = (float)Sss[idx]; Sss[idx] = (bf16_t)r2; r2 += t2;
        }
    }
    if (threadIdx.x < HD) {
        int e = threadIdx.x;
        float r1 = 0.f, r2 = 0.f;
        for (int c = 0; c < NCHUNK; ++c) {
            int idx = (bh * NCHUNK + c) * HD + e;
            float t1 = zc[idx]; zc[idx] = r1; r1 += t1;
            float t2 = zs[idx]; zs[idx] = r2; r2 += t2;
        }
    }
}

// ---------------------------------------------------------------------------
// K4 (MFMA rewrite): per-chunk output.
//   P = (q' k'^T) * cosd[t-s], causal-masked  -> bf16 LDS (rows wave-local)
//   ctx = P @ V + q'c @ Sc + q's @ Ss         -> 3 fused MFMA streams
//   nrm[t] = sum_s P[t][s] + q'[t].(cw*zc + sw*zs)
//   Y[b, tg, h*64+e] = ctx/(nrm+eps)
// One barrier total: all post-staging data deps are wave-local.
// ---------------------------------------------------------------------------
__global__ __launch_bounds__(256) void chunk_out_kernel(
    const bf16_t* __restrict__ qq, const bf16_t* __restrict__ kk,
    const bf16_t* __restrict__ vv,
    const bf16_t* __restrict__ SscT, const bf16_t* __restrict__ SssT,
    const float* __restrict__ zc, const float* __restrict__ zs,
    bf16_t* __restrict__ Y)
{
    const int blk = blockIdx.x;
    const int bh = blk >> 4, ch = blk & 15;
    __shared__ __align__(16) bf16_t sq [CHUNK * LDA];  // q' rows
    __shared__ __align__(16) bf16_t sk [CHUNK * LDA];  // k' rows
    __shared__ __align__(16) bf16_t svT[CHUNK * LDA];  // svT[e][s] = v[s][e]
    __shared__ __align__(16) bf16_t sct[CHUNK * LDA];  // ScT[e][i]
    __shared__ __align__(16) bf16_t sst[CHUNK * LDA];  // SsT[e][i]
    __shared__ __align__(16) bf16_t sp [CHUNK * LDA];  // masked/scaled P rows
    __shared__ float cwt[CHUNK], swt[CHUNK], cosd[CHUNK];
    __shared__ float zcl[CHUNK], zsl[CHUNK], nrm[CHUNK];

    const int base = blk * CHUNK * HD;
    // staging: 512 uint4 per matrix, 256 threads -> 2 each
    for (int i = threadIdx.x; i < CHUNK * HD / 8; i += 256) {
        int row = i >> 3, g = i & 7;
        ((uint4*)(sq + row * LDA))[g]  = ((const uint4*)(qq + base))[i];
        ((uint4*)(sk + row * LDA))[g]  = ((const uint4*)(kk + base))[i];
        ((uint4*)(sct + row * LDA))[g] = ((const uint4*)(SscT + base))[i];
        ((uint4*)(sst + row * LDA))[g] = ((const uint4*)(SssT + base))[i];
        // V transposed: flat elem f = i*8+j -> t = i>>3, e = (i&7)*8+j
        bf16x8 v8 = *(const bf16x8*)(vv + base + i * 8);
        int t = i >> 3, e0 = (i & 7) * 8;
        for (int j = 0; j < 8; ++j) svT[(e0 + j) * LDA + t] = v8[j];
    }
    if (threadIdx.x < CHUNK) {
        int tl = threadIdx.x;
        int tg = ch * CHUNK + tl;
        float angg = 1.5707963267948966f * (float)tg * (1.0f / (float)T_SEQ);
        cwt[tl] = cosf(angg);
        swt[tl] = sinf(angg);
        cosd[tl] = cosf(1.5707963267948966f * (float)tl * (1.0f / (float)T_SEQ));
        zcl[tl] = zc[blk * HD + tl];
        zsl[tl] = zs[blk * HD + tl];
    }
    __syncthreads();

    const int w = threadIdx.x >> 6;
    const int lane = threadIdx.x & 63;
    const int rsel = lane & 15;
    const int koff = (lane >> 4) * 8;
    const int myrow = w * 16 + rsel;          // A-frag row (wave-local)

    // ---- Stage A: P = q' k'^T, scale+mask, store bf16 rows (wave-local) ----
    bf16x8 aq0 = *(const bf16x8*)(sq + myrow * LDA + koff);
    bf16x8 aq1 = *(const bf16x8*)(sq + myrow * LDA + koff + 32);
    for (int nt = 0; nt < 4; ++nt) {
        const int n0 = nt * 16;
        f32x4 pacc = {0.f, 0.f, 0.f, 0.f};
        bf16x8 b0 = *(const bf16x8*)(sk + (n0 + rsel) * LDA + koff);
        bf16x8 b1 = *(const bf16x8*)(sk + (n0 + rsel) * LDA + koff + 32);
        pacc = __builtin_amdgcn_mfma_f32_16x16x32_bf16(aq0, b0, pacc, 0, 0, 0);
        pacc = __builtin_amdgcn_mfma_f32_16x16x32_bf16(aq1, b1, pacc, 0, 0, 0);
        const int s = n0 + (lane & 15);
        const int tb = w * 16 + (lane >> 4) * 4;
        for (int r = 0; r < 4; ++r) {
            int t = tb + r;
            float p = (s <= t) ? pacc[r] * cosd[t - s] : 0.f;
            sp[t * LDA + s] = (bf16_t)p;
        }
    }

    // ---- nrm (lanes 0..15 of each wave; rows wave-local) ----
    if (rsel == lane) { /* always true; keep lanes<16 */ }
    if (lane < 16) {
        int row = w * 16 + lane;
        float nv = 0.f;
        const bf16x8* pr = (const bf16x8*)(sp + row * LDA);
        for (int g = 0; g < 8; ++g) {
            bf16x8 pv = pr[g];
            for (int j = 0; j < 8; ++j) nv += (float)pv[j];
        }
        float cwr = cwt[row], swr = swt[row];
        const bf16x8* qr = (const bf16x8*)(sq + row * LDA);
        for (int g = 0; g < 8; ++g) {
            bf16x8 qv = qr[g];
            for (int j = 0; j < 8; ++j)
                nv += (float)qv[j] * (cwr * zcl[g * 8 + j] + swr * zsl[g * 8 + j]);
        }
        nrm[row] = nv;
    }

    // ---- Stage C: ctx = P@V + q'c@Sc + q's@Ss ----
    const float cwq = cwt[myrow], swq = swt[myrow];
    bf16x8 qc0, qc1, qs0, qs1;
    for (int j = 0; j < 8; ++j) {
        qc0[j] = (bf16_t)((float)aq0[j] * cwq);
        qc1[j] = (bf16_t)((float)aq1[j] * cwq);
        qs0[j] = (bf16_t)((float)aq0[j] * swq);
        qs1[j] = (bf16_t)((float)aq1[j] * swq);
    }
    bf16x8 ap0 = *(const bf16x8*)(sp + myrow * LDA + koff);
    bf16x8 ap1 = *(const bf16x8*)(sp + myrow * LDA + koff + 32);

    const int b = bh >> 3, h = bh & 7;
    for (int nt = 0; nt < 4; ++nt) {
        const int n0 = nt * 16;
        const bf16_t* bvp = svT + (n0 + rsel) * LDA + koff;
        const bf16_t* bcp = sct + (n0 + rsel) * LDA + koff;
        const bf16_t* bsp = sst + (n0 + rsel) * LDA + koff;
        f32x4 acc = {0.f, 0.f, 0.f, 0.f};
        acc = __builtin_amdgcn_mfma_f32_16x16x32_bf16(ap0, *(const bf16x8*)(bvp), acc, 0, 0, 0);
        acc = __builtin_amdgcn_mfma_f32_16x16x32_bf16(ap1, *(const bf16x8*)(bvp + 32), acc, 0, 0, 0);
        acc = __builtin_amdgcn_mfma_f32_16x16x32_bf16(qc0, *(const bf16x8*)(bcp), acc, 0, 0, 0);
        acc = __builtin_amdgcn_mfma_f32_16x16x32_bf16(qc1, *(const bf16x8*)(bcp + 32), acc, 0, 0, 0);
        acc = __builtin_amdgcn_mfma_f32_16x16x32_bf16(qs0, *(const bf16x8*)(bsp), acc, 0, 0, 0);
        acc = __builtin_amdgcn_mfma_f32_16x16x32_bf16(qs1, *(const bf16x8*)(bsp + 32), acc, 0, 0, 0);
        const int col = n0 + (lane & 15);
        const int tb = w * 16 + (lane >> 4) * 4;
        for (int r = 0; r < 4; ++r) {
            int row = tb + r;
            float inv = 1.0f / (nrm[row] + 1e-6f);
            int tg = ch * CHUNK + row;
            Y[((b * T_SEQ + tg) * EMB) + h * HD + col] = (bf16_t)(acc[r] * inv);
        }
    }
}

// ---------------------------------------------------------------------------
// K5: out = Y @ w_out^T + b_out. fp32 output.
// ---------------------------------------------------------------------------
__global__ __launch_bounds__(256) void out_gemm_kernel(
    const bf16_t* __restrict__ Yb, const bf16_t* __restrict__ W,
    const float* __restrict__ bias, float* __restrict__ out)
{
    const int wave = threadIdx.x >> 6;
    const int lane = threadIdx.x & 63;
    const int m0 = blockIdx.x * 16;
    const int n0 = blockIdx.y * 64 + wave * 16;
    const int rsel = lane & 15;
    const int koff = (lane >> 4) * 8;
    f32x4 acc = {0.f, 0.f, 0.f, 0.f};
    const bf16_t* Ap = Yb + (m0 + rsel) * EMB + koff;
    const bf16_t* Bp = W + (n0 + rsel) * EMB + koff;
    for (int k0 = 0; k0 < EMB; k0 += 32) {
        bf16x8 af = *reinterpret_cast<const bf16x8*>(Ap + k0);
        bf16x8 bfv = *reinterpret_cast<const bf16x8*>(Bp + k0);
        acc = __builtin_amdgcn_mfma_f32_16x16x32_bf16(af, bfv, acc, 0, 0, 0);
    }
    const int n = n0 + (lane & 15);
    const int mb = m0 + (lane >> 4) * 4;
    const float bn = bias[n];
    for (int r = 0; r < 4; ++r) {
        int m = mb + r;
        out[m * EMB + n] = acc[r] + bn;
    }
}

extern "C" void kernel_launch(void* const* d_in, const int* in_sizes, int n_in,
                              void* d_out, int out_size, void* d_ws, size_t ws_size,
                              hipStream_t stream) {
    const float* x     = (const float*)d_in[0];
    const float* w_qkv = (const float*)d_in[1];
    const float* b_qkv = (const float*)d_in[2];
    const float* w_out = (const float*)d_in[3];
    const float* b_out = (const float*)d_in[4];
    float* out = (float*)d_out;

    char* w = (char*)d_ws;
    const size_t N_X   = (size_t)BATCH * T_SEQ * EMB;
    const size_t N_WQ  = (size_t)3 * EMB * EMB;
    const size_t N_WO  = (size_t)EMB * EMB;
    bf16_t* xb   = (bf16_t*)w;                 w += N_X  * sizeof(bf16_t);
    bf16_t* wqb  = (bf16_t*)w;                 w += N_WQ * sizeof(bf16_t);
    bf16_t* wob  = (bf16_t*)w;                 w += N_WO * sizeof(bf16_t);
    const size_t SZ_BHTD = (size_t)NBH * T_SEQ * HD * sizeof(bf16_t); // 2 MB
    bf16_t* qq = (bf16_t*)w;                   w += SZ_BHTD;
    bf16_t* kk = (bf16_t*)w;                   w += SZ_BHTD;
    bf16_t* vv = (bf16_t*)w;                   w += SZ_BHTD;
    bf16_t* Y  = (bf16_t*)w;                   w += SZ_BHTD;
    bf16_t* Ssc = (bf16_t*)w;                  w += (size_t)NBLK * HD * HD * sizeof(bf16_t);
    bf16_t* Sss = (bf16_t*)w;                  w += (size_t)NBLK * HD * HD * sizeof(bf16_t);
    float* zc = (float*)w;                     w += (size_t)NBLK * HD * sizeof(float);
    float* zs = (float*)w;

    cvt_kernel<<<(int)(N_X / 4 + 255) / 256, 256, 0, stream>>>(x, xb, (int)(N_X / 4));
    cvt_kernel<<<(int)(N_WQ / 4 + 255) / 256, 256, 0, stream>>>(w_qkv, wqb, (int)(N_WQ / 4));
    cvt_kernel<<<(int)(N_WO / 4 + 255) / 256, 256, 0, stream>>>(w_out, wob, (int)(N_WO / 4));

    qkv_gemm_kernel<<<dim3(2048 / 16, 1536 / 64), 256, 0, stream>>>(
        xb, wqb, b_qkv, qq, kk, vv);
    chunk_sum_kernel<<<NBLK, 256, 0, stream>>>(kk, vv, Ssc, Sss, zc, zs);
    scan_kernel<<<NBH, 256, 0, stream>>>(Ssc, Sss, zc, zs);
    chunk_out_kernel<<<NBLK, 256, 0, stream>>>(qq, kk, vv, Ssc, Sss, zc, zs, Y);
    out_gemm_kernel<<<dim3(2048 / 16, 512 / 64), 256, 0, stream>>>(
        Y, wob, b_out, out);
}

// Round 5
// 139.222 us; speedup vs baseline: 1.5027x; 1.2272x over previous
//
#include <hip/hip_runtime.h>

typedef __bf16 bf16_t;
typedef __bf16 bf16x4 __attribute__((ext_vector_type(4)));
typedef __bf16 bf16x8 __attribute__((ext_vector_type(8)));
typedef float f32x4 __attribute__((ext_vector_type(4)));

#define T_SEQ 1024
#define EMB   512
#define NH    8
#define HD    64
#define BATCH 2
#define NBH   (BATCH*NH)      // 16
#define CHUNK 64
#define NCHUNK (T_SEQ/CHUNK)  // 16
#define NBLK  (NBH*NCHUNK)    // 256
#define LDA   72              // padded LDS row stride

// Identity: with ang_t = (pi/2)*t/T,
//   q_cos[t].k_cos[s] + q_sin[t].k_sin[s] = (q'[t].k'[s]) * cos(ang_t - ang_s)

// ---------------------------------------------------------------------------
// K0: fp32 -> bf16 convert.
// ---------------------------------------------------------------------------
__global__ __launch_bounds__(256) void cvt_kernel(
    const float* __restrict__ src, bf16_t* __restrict__ dst, int n4)
{
    int i = blockIdx.x * 256 + threadIdx.x;
    if (i < n4) {
        float4 v = ((const float4*)src)[i];
        bf16x4 o;
        o[0] = (bf16_t)v.x; o[1] = (bf16_t)v.y;
        o[2] = (bf16_t)v.z; o[3] = (bf16_t)v.w;
        ((bf16x4*)dst)[i] = o;
    }
}

// ---------------------------------------------------------------------------
// K1 v2: qkv GEMM, register-blocked. 128x128 block tile, 4 waves 2x2,
// wave = 64x64 = 4x4 MFMA tiles (16 independent acc chains).
// ---------------------------------------------------------------------------
__global__ __launch_bounds__(256) void qkv_gemm_kernel(
    const bf16_t* __restrict__ X, const bf16_t* __restrict__ W,
    const float* __restrict__ bias,
    bf16_t* __restrict__ qq, bf16_t* __restrict__ kk, bf16_t* __restrict__ vv)
{
    const int w = threadIdx.x >> 6;
    const int lane = threadIdx.x & 63;
    const int rsel = lane & 15;
    const int koff = (lane >> 4) * 8;
    const int m0 = blockIdx.x * 128 + (w & 1) * 64;
    const int n0 = blockIdx.y * 128 + (w >> 1) * 64;
    f32x4 acc[4][4] = {};
    const bf16_t* Ap = X + (m0 + rsel) * EMB + koff;
    const bf16_t* Bp = W + (n0 + rsel) * EMB + koff;
#pragma unroll 2
    for (int k0 = 0; k0 < EMB; k0 += 32) {
        bf16x8 af[4], bfr[4];
        for (int i = 0; i < 4; ++i)
            af[i] = *(const bf16x8*)(Ap + i * 16 * EMB + k0);
        for (int j = 0; j < 4; ++j)
            bfr[j] = *(const bf16x8*)(Bp + j * 16 * EMB + k0);
        for (int i = 0; i < 4; ++i)
            for (int j = 0; j < 4; ++j)
                acc[i][j] = __builtin_amdgcn_mfma_f32_16x16x32_bf16(
                    af[i], bfr[j], acc[i][j], 0, 0, 0);
    }
    for (int j = 0; j < 4; ++j) {
        const int n = n0 + j * 16 + rsel;
        const float bn = bias[n];
        const int sec = n >> 9;          // 0=q 1=k 2=v
        const int c = n & 511;
        const int h = c >> 6, e = c & 63;
        for (int i = 0; i < 4; ++i) {
            const int mb = m0 + i * 16 + (lane >> 4) * 4;
            for (int r = 0; r < 4; ++r) {
                int m = mb + r;
                int b = m >> 10, t = m & 1023;
                float val = acc[i][j][r] + bn;
                int di = ((b * NH + h) * T_SEQ + t) * HD + e;
                if (sec == 0) {
                    qq[di] = (bf16_t)fmaxf(val, 0.f);
                } else if (sec == 1) {
                    kk[di] = (bf16_t)fmaxf(val, 0.f);
                } else {
                    vv[di] = (bf16_t)val;
                }
            }
        }
    }
}

// ---------------------------------------------------------------------------
// K2: per-chunk weighted sums, stored TRANSPOSED for K4's MFMA B-operand.
// ---------------------------------------------------------------------------
__global__ __launch_bounds__(256) void chunk_sum_kernel(
    const bf16_t* __restrict__ kk, const bf16_t* __restrict__ vv,
    bf16_t* __restrict__ Ssc, bf16_t* __restrict__ Sss,
    float* __restrict__ zc, float* __restrict__ zs)
{
    const int blk = blockIdx.x;
    const int ch = blk & 15;
    __shared__ __align__(16) bf16_t sk[CHUNK * HD];
    __shared__ __align__(16) bf16_t sv[CHUNK * HD];
    __shared__ float cwt[CHUNK], swt[CHUNK];
    const int base = blk * CHUNK * HD;
    for (int i = threadIdx.x; i < CHUNK * HD / 8; i += 256) {
        ((uint4*)sk)[i] = ((const uint4*)(kk + base))[i];
        ((uint4*)sv)[i] = ((const uint4*)(vv + base))[i];
    }
    if (threadIdx.x < CHUNK) {
        int tg = ch * CHUNK + threadIdx.x;
        float ang = 1.5707963267948966f * (float)tg * (1.0f / (float)T_SEQ);
        cwt[threadIdx.x] = cosf(ang);
        swt[threadIdx.x] = sinf(ang);
    }
    __syncthreads();
    const int i  = threadIdx.x & 63;
    const int jg = (threadIdx.x >> 6) * 16;
    float ac[16], as[16];
    for (int jj = 0; jj < 16; ++jj) { ac[jj] = 0.f; as[jj] = 0.f; }
    for (int t = 0; t < CHUNK; ++t) {
        float kv = (float)sk[t * HD + i];
        float kc_ = kv * cwt[t];
        float ks_ = kv * swt[t];
        for (int jj = 0; jj < 16; ++jj) {
            float vj = (float)sv[t * HD + jg + jj];
            ac[jj] += kc_ * vj;
            as[jj] += ks_ * vj;
        }
    }
    bf16_t* oc = Ssc + blk * HD * HD;
    bf16_t* os = Sss + blk * HD * HD;
    for (int jj = 0; jj < 16; ++jj) {
        oc[(jg + jj) * HD + i] = (bf16_t)ac[jj];   // transposed: [e][i]
        os[(jg + jj) * HD + i] = (bf16_t)as[jj];
    }
    if (threadIdx.x < HD) {
        int ii = threadIdx.x;
        float s = 0.f;
        for (int t = 0; t < CHUNK; ++t) s += (float)sk[t * HD + ii] * cwt[t];
        zc[blk * HD + ii] = s;
    } else if (threadIdx.x < 2 * HD) {
        int ii = threadIdx.x - HD;
        float s = 0.f;
        for (int t = 0; t < CHUNK; ++t) s += (float)sk[t * HD + ii] * swt[t];
        zs[blk * HD + ii] = s;
    }
}

// ---------------------------------------------------------------------------
// K3: in-place exclusive prefix scan over chunks per bh.
// ---------------------------------------------------------------------------
__global__ __launch_bounds__(256) void scan_kernel(
    bf16_t* __restrict__ Ssc, bf16_t* __restrict__ Sss,
    float* __restrict__ zc, float* __restrict__ zs)
{
    const int bh = blockIdx.x;
    for (int e = threadIdx.x; e < HD * HD; e += 256) {
        float r1 = 0.f, r2 = 0.f;
        for (int c = 0; c < NCHUNK; ++c) {
            int idx = (bh * NCHUNK + c) * HD * HD + e;
            float t1 = (float)Ssc[idx]; Ssc[idx] = (bf16_t)r1; r1 += t1;
            float t2 = (float)Sss[idx]; Sss[idx] = (bf16_t)r2; r2 += t2;
        }
    }
    if (threadIdx.x < HD) {
        int e = threadIdx.x;
        float r1 = 0.f, r2 = 0.f;
        for (int c = 0; c < NCHUNK; ++c) {
            int idx = (bh * NCHUNK + c) * HD + e;
            float t1 = zc[idx]; zc[idx] = r1; r1 += t1;
            float t2 = zs[idx]; zs[idx] = r2; r2 += t2;
        }
    }
}

// ---------------------------------------------------------------------------
// K4 (MFMA): per-chunk output. One barrier; post-staging deps wave-local.
// ---------------------------------------------------------------------------
__global__ __launch_bounds__(256) void chunk_out_kernel(
    const bf16_t* __restrict__ qq, const bf16_t* __restrict__ kk,
    const bf16_t* __restrict__ vv,
    const bf16_t* __restrict__ SscT, const bf16_t* __restrict__ SssT,
    const float* __restrict__ zc, const float* __restrict__ zs,
    bf16_t* __restrict__ Y)
{
    const int blk = blockIdx.x;
    const int bh = blk >> 4, ch = blk & 15;
    __shared__ __align__(16) bf16_t sq [CHUNK * LDA];
    __shared__ __align__(16) bf16_t sk [CHUNK * LDA];
    __shared__ __align__(16) bf16_t svT[CHUNK * LDA];
    __shared__ __align__(16) bf16_t sct[CHUNK * LDA];
    __shared__ __align__(16) bf16_t sst[CHUNK * LDA];
    __shared__ __align__(16) bf16_t sp [CHUNK * LDA];
    __shared__ float cwt[CHUNK], swt[CHUNK], cosd[CHUNK];
    __shared__ float zcl[CHUNK], zsl[CHUNK], nrm[CHUNK];

    const int base = blk * CHUNK * HD;
    for (int i = threadIdx.x; i < CHUNK * HD / 8; i += 256) {
        int row = i >> 3, g = i & 7;
        ((uint4*)(sq + row * LDA))[g]  = ((const uint4*)(qq + base))[i];
        ((uint4*)(sk + row * LDA))[g]  = ((const uint4*)(kk + base))[i];
        ((uint4*)(sct + row * LDA))[g] = ((const uint4*)(SscT + base))[i];
        ((uint4*)(sst + row * LDA))[g] = ((const uint4*)(SssT + base))[i];
        bf16x8 v8 = *(const bf16x8*)(vv + base + i * 8);
        int t = i >> 3, e0 = (i & 7) * 8;
        for (int j = 0; j < 8; ++j) svT[(e0 + j) * LDA + t] = v8[j];
    }
    if (threadIdx.x < CHUNK) {
        int tl = threadIdx.x;
        int tg = ch * CHUNK + tl;
        float angg = 1.5707963267948966f * (float)tg * (1.0f / (float)T_SEQ);
        cwt[tl] = cosf(angg);
        swt[tl] = sinf(angg);
        cosd[tl] = cosf(1.5707963267948966f * (float)tl * (1.0f / (float)T_SEQ));
        zcl[tl] = zc[blk * HD + tl];
        zsl[tl] = zs[blk * HD + tl];
    }
    __syncthreads();

    const int w = threadIdx.x >> 6;
    const int lane = threadIdx.x & 63;
    const int rsel = lane & 15;
    const int koff = (lane >> 4) * 8;
    const int myrow = w * 16 + rsel;

    bf16x8 aq0 = *(const bf16x8*)(sq + myrow * LDA + koff);
    bf16x8 aq1 = *(const bf16x8*)(sq + myrow * LDA + koff + 32);
    for (int nt = 0; nt < 4; ++nt) {
        const int n0 = nt * 16;
        f32x4 pacc = {0.f, 0.f, 0.f, 0.f};
        bf16x8 b0 = *(const bf16x8*)(sk + (n0 + rsel) * LDA + koff);
        bf16x8 b1 = *(const bf16x8*)(sk + (n0 + rsel) * LDA + koff + 32);
        pacc = __builtin_amdgcn_mfma_f32_16x16x32_bf16(aq0, b0, pacc, 0, 0, 0);
        pacc = __builtin_amdgcn_mfma_f32_16x16x32_bf16(aq1, b1, pacc, 0, 0, 0);
        const int s = n0 + (lane & 15);
        const int tb = w * 16 + (lane >> 4) * 4;
        for (int r = 0; r < 4; ++r) {
            int t = tb + r;
            float p = (s <= t) ? pacc[r] * cosd[t - s] : 0.f;
            sp[t * LDA + s] = (bf16_t)p;
        }
    }

    if (lane < 16) {
        int row = w * 16 + lane;
        float nv = 0.f;
        const bf16x8* pr = (const bf16x8*)(sp + row * LDA);
        for (int g = 0; g < 8; ++g) {
            bf16x8 pv = pr[g];
            for (int j = 0; j < 8; ++j) nv += (float)pv[j];
        }
        float cwr = cwt[row], swr = swt[row];
        const bf16x8* qr = (const bf16x8*)(sq + row * LDA);
        for (int g = 0; g < 8; ++g) {
            bf16x8 qv = qr[g];
            for (int j = 0; j < 8; ++j)
                nv += (float)qv[j] * (cwr * zcl[g * 8 + j] + swr * zsl[g * 8 + j]);
        }
        nrm[row] = nv;
    }

    const float cwq = cwt[myrow], swq = swt[myrow];
    bf16x8 qc0, qc1, qs0, qs1;
    for (int j = 0; j < 8; ++j) {
        qc0[j] = (bf16_t)((float)aq0[j] * cwq);
        qc1[j] = (bf16_t)((float)aq1[j] * cwq);
        qs0[j] = (bf16_t)((float)aq0[j] * swq);
        qs1[j] = (bf16_t)((float)aq1[j] * swq);
    }
    bf16x8 ap0 = *(const bf16x8*)(sp + myrow * LDA + koff);
    bf16x8 ap1 = *(const bf16x8*)(sp + myrow * LDA + koff + 32);

    const int b = bh >> 3, h = bh & 7;
    for (int nt = 0; nt < 4; ++nt) {
        const int n0 = nt * 16;
        const bf16_t* bvp = svT + (n0 + rsel) * LDA + koff;
        const bf16_t* bcp = sct + (n0 + rsel) * LDA + koff;
        const bf16_t* bsp = sst + (n0 + rsel) * LDA + koff;
        f32x4 acc = {0.f, 0.f, 0.f, 0.f};
        acc = __builtin_amdgcn_mfma_f32_16x16x32_bf16(ap0, *(const bf16x8*)(bvp), acc, 0, 0, 0);
        acc = __builtin_amdgcn_mfma_f32_16x16x32_bf16(ap1, *(const bf16x8*)(bvp + 32), acc, 0, 0, 0);
        acc = __builtin_amdgcn_mfma_f32_16x16x32_bf16(qc0, *(const bf16x8*)(bcp), acc, 0, 0, 0);
        acc = __builtin_amdgcn_mfma_f32_16x16x32_bf16(qc1, *(const bf16x8*)(bcp + 32), acc, 0, 0, 0);
        acc = __builtin_amdgcn_mfma_f32_16x16x32_bf16(qs0, *(const bf16x8*)(bsp), acc, 0, 0, 0);
        acc = __builtin_amdgcn_mfma_f32_16x16x32_bf16(qs1, *(const bf16x8*)(bsp + 32), acc, 0, 0, 0);
        const int col = n0 + (lane & 15);
        const int tb = w * 16 + (lane >> 4) * 4;
        for (int r = 0; r < 4; ++r) {
            int row = tb + r;
            float inv = 1.0f / (nrm[row] + 1e-6f);
            int tg = ch * CHUNK + row;
            Y[((b * T_SEQ + tg) * EMB) + h * HD + col] = (bf16_t)(acc[r] * inv);
        }
    }
}

// ---------------------------------------------------------------------------
// K5 v2: out = Y @ w_out^T + b_out, register-blocked. 64x64 block tile,
// 4 waves 2x2, wave = 32x32 = 2x2 MFMA tiles.
// ---------------------------------------------------------------------------
__global__ __launch_bounds__(256) void out_gemm_kernel(
    const bf16_t* __restrict__ Yb, const bf16_t* __restrict__ W,
    const float* __restrict__ bias, float* __restrict__ out)
{
    const int w = threadIdx.x >> 6;
    const int lane = threadIdx.x & 63;
    const int rsel = lane & 15;
    const int koff = (lane >> 4) * 8;
    const int m0 = blockIdx.x * 64 + (w & 1) * 32;
    const int n0 = blockIdx.y * 64 + (w >> 1) * 32;
    f32x4 acc[2][2] = {};
    const bf16_t* Ap = Yb + (m0 + rsel) * EMB + koff;
    const bf16_t* Bp = W + (n0 + rsel) * EMB + koff;
#pragma unroll 2
    for (int k0 = 0; k0 < EMB; k0 += 32) {
        bf16x8 af[2], bfr[2];
        for (int i = 0; i < 2; ++i)
            af[i] = *(const bf16x8*)(Ap + i * 16 * EMB + k0);
        for (int j = 0; j < 2; ++j)
            bfr[j] = *(const bf16x8*)(Bp + j * 16 * EMB + k0);
        for (int i = 0; i < 2; ++i)
            for (int j = 0; j < 2; ++j)
                acc[i][j] = __builtin_amdgcn_mfma_f32_16x16x32_bf16(
                    af[i], bfr[j], acc[i][j], 0, 0, 0);
    }
    for (int j = 0; j < 2; ++j) {
        const int n = n0 + j * 16 + rsel;
        const float bn = bias[n];
        for (int i = 0; i < 2; ++i) {
            const int mb = m0 + i * 16 + (lane >> 4) * 4;
            for (int r = 0; r < 4; ++r)
                out[(mb + r) * EMB + n] = acc[i][j][r] + bn;
        }
    }
}

extern "C" void kernel_launch(void* const* d_in, const int* in_sizes, int n_in,
                              void* d_out, int out_size, void* d_ws, size_t ws_size,
                              hipStream_t stream) {
    const float* x     = (const float*)d_in[0];
    const float* w_qkv = (const float*)d_in[1];
    const float* b_qkv = (const float*)d_in[2];
    const float* w_out = (const float*)d_in[3];
    const float* b_out = (const float*)d_in[4];
    float* out = (float*)d_out;

    char* w = (char*)d_ws;
    const size_t N_X   = (size_t)BATCH * T_SEQ * EMB;
    const size_t N_WQ  = (size_t)3 * EMB * EMB;
    const size_t N_WO  = (size_t)EMB * EMB;
    bf16_t* xb   = (bf16_t*)w;                 w += N_X  * sizeof(bf16_t);
    bf16_t* wqb  = (bf16_t*)w;                 w += N_WQ * sizeof(bf16_t);
    bf16_t* wob  = (bf16_t*)w;                 w += N_WO * sizeof(bf16_t);
    const size_t SZ_BHTD = (size_t)NBH * T_SEQ * HD * sizeof(bf16_t);
    bf16_t* qq = (bf16_t*)w;                   w += SZ_BHTD;
    bf16_t* kk = (bf16_t*)w;                   w += SZ_BHTD;
    bf16_t* vv = (bf16_t*)w;                   w += SZ_BHTD;
    bf16_t* Y  = (bf16_t*)w;                   w += SZ_BHTD;
    bf16_t* Ssc = (bf16_t*)w;                  w += (size_t)NBLK * HD * HD * sizeof(bf16_t);
    bf16_t* Sss = (bf16_t*)w;                  w += (size_t)NBLK * HD * HD * sizeof(bf16_t);
    float* zc = (float*)w;                     w += (size_t)NBLK * HD * sizeof(float);
    float* zs = (float*)w;

    cvt_kernel<<<(int)(N_X / 4 + 255) / 256, 256, 0, stream>>>(x, xb, (int)(N_X / 4));
    cvt_kernel<<<(int)(N_WQ / 4 + 255) / 256, 256, 0, stream>>>(w_qkv, wqb, (int)(N_WQ / 4));
    cvt_kernel<<<(int)(N_WO / 4 + 255) / 256, 256, 0, stream>>>(w_out, wob, (int)(N_WO / 4));

    qkv_gemm_kernel<<<dim3(2048 / 128, 1536 / 128), 256, 0, stream>>>(
        xb, wqb, b_qkv, qq, kk, vv);
    chunk_sum_kernel<<<NBLK, 256, 0, stream>>>(kk, vv, Ssc, Sss, zc, zs);
    scan_kernel<<<NBH, 256, 0, stream>>>(Ssc, Sss, zc, zs);
    chunk_out_kernel<<<NBLK, 256, 0, stream>>>(qq, kk, vv, Ssc, Sss, zc, zs, Y);
    out_gemm_kernel<<<dim3(2048 / 64, 512 / 64), 256, 0, stream>>>(
        Y, wob, b_out, out);
}

// Round 7
// 126.678 us; speedup vs baseline: 1.6515x; 1.0990x over previous
//
#include <hip/hip_runtime.h>

typedef __bf16 bf16_t;
typedef __bf16 bf16x4 __attribute__((ext_vector_type(4)));
typedef __bf16 bf16x8 __attribute__((ext_vector_type(8)));
typedef float f32x4 __attribute__((ext_vector_type(4)));

#define T_SEQ 1024
#define EMB   512
#define NH    8
#define HD    64
#define BATCH 2
#define NBH   (BATCH*NH)      // 16
#define CHUNK 64
#define NCHUNK (T_SEQ/CHUNK)  // 16
#define NBLK  (NBH*NCHUNK)    // 256
#define LDA   72              // padded LDS row stride

// Identity: with ang_t = (pi/2)*t/T,
//   q_cos[t].k_cos[s] + q_sin[t].k_sin[s] = (q'[t].k'[s]) * cos(ang_t - ang_s)

// ---------------------------------------------------------------------------
// K0: fused fp32 -> bf16 convert for x, w_qkv, w_out (one dispatch).
// float4 units: x 262144 | w_qkv 196608 | w_out 65536 -> total 524288.
// ---------------------------------------------------------------------------
__global__ __launch_bounds__(256) void cvt3_kernel(
    const float* __restrict__ x, const float* __restrict__ wq,
    const float* __restrict__ wo,
    bf16_t* __restrict__ xb, bf16_t* __restrict__ wqb, bf16_t* __restrict__ wob)
{
    int i = blockIdx.x * 256 + threadIdx.x;
    const float* s; bf16_t* d; int off;
    if (i < 262144)      { s = x;  d = xb;  off = i; }
    else if (i < 458752) { s = wq; d = wqb; off = i - 262144; }
    else                 { s = wo; d = wob; off = i - 458752; }
    float4 v = ((const float4*)s)[off];
    bf16x4 o;
    o[0] = (bf16_t)v.x; o[1] = (bf16_t)v.y;
    o[2] = (bf16_t)v.z; o[3] = (bf16_t)v.w;
    ((bf16x4*)d)[off] = o;
}

// ---------------------------------------------------------------------------
// K1 (R5-proven): qkv GEMM, 128x128 block tile, 4 waves 2x2, wave 64x64.
// q,k relu'd row-major [bh][t][e]; v row-major [bh][t][e].
// ---------------------------------------------------------------------------
__global__ __launch_bounds__(256) void qkv_gemm_kernel(
    const bf16_t* __restrict__ X, const bf16_t* __restrict__ W,
    const float* __restrict__ bias,
    bf16_t* __restrict__ qq, bf16_t* __restrict__ kk, bf16_t* __restrict__ vv)
{
    const int w = threadIdx.x >> 6;
    const int lane = threadIdx.x & 63;
    const int rsel = lane & 15;
    const int koff = (lane >> 4) * 8;
    const int m0 = blockIdx.x * 128 + (w & 1) * 64;
    const int n0 = blockIdx.y * 128 + (w >> 1) * 64;
    f32x4 acc[4][4] = {};
    const bf16_t* Ap = X + (m0 + rsel) * EMB + koff;
    const bf16_t* Bp = W + (n0 + rsel) * EMB + koff;
#pragma unroll 2
    for (int k0 = 0; k0 < EMB; k0 += 32) {
        bf16x8 af[4], bfr[4];
        for (int i = 0; i < 4; ++i)
            af[i] = *(const bf16x8*)(Ap + i * 16 * EMB + k0);
        for (int j = 0; j < 4; ++j)
            bfr[j] = *(const bf16x8*)(Bp + j * 16 * EMB + k0);
        for (int i = 0; i < 4; ++i)
            for (int j = 0; j < 4; ++j)
                acc[i][j] = __builtin_amdgcn_mfma_f32_16x16x32_bf16(
                    af[i], bfr[j], acc[i][j], 0, 0, 0);
    }
    for (int j = 0; j < 4; ++j) {
        const int n = n0 + j * 16 + rsel;
        const float bn = bias[n];
        const int sec = n >> 9;          // 0=q 1=k 2=v
        const int c = n & 511;
        const int h = c >> 6, e = c & 63;
        for (int i = 0; i < 4; ++i) {
            const int mb = m0 + i * 16 + (lane >> 4) * 4;
            for (int r = 0; r < 4; ++r) {
                int m = mb + r;
                int b = m >> 10, t = m & 1023;
                float val = acc[i][j][r] + bn;
                int di = ((b * NH + h) * T_SEQ + t) * HD + e;
                if (sec == 0) {
                    qq[di] = (bf16_t)fmaxf(val, 0.f);
                } else if (sec == 1) {
                    kk[di] = (bf16_t)fmaxf(val, 0.f);
                } else {
                    vv[di] = (bf16_t)val;
                }
            }
        }
    }
}

// ---------------------------------------------------------------------------
// K2 (R5-proven VALU): per-chunk weighted sums, S stored TRANSPOSED [e][i]:
//   SscT[blk][e][i] = sum_t cw_t*k'[t][i]*v[t][e]   (bf16)
//   zc[blk][i]      = sum_t cw_t*k'[t][i]           (fp32, full-precision products)
// ---------------------------------------------------------------------------
__global__ __launch_bounds__(256) void chunk_sum_kernel(
    const bf16_t* __restrict__ kk, const bf16_t* __restrict__ vv,
    bf16_t* __restrict__ Ssc, bf16_t* __restrict__ Sss,
    float* __restrict__ zc, float* __restrict__ zs)
{
    const int blk = blockIdx.x;
    const int ch = blk & 15;
    __shared__ __align__(16) bf16_t sk[CHUNK * HD];
    __shared__ __align__(16) bf16_t sv[CHUNK * HD];
    __shared__ float cwt[CHUNK], swt[CHUNK];
    const int base = blk * CHUNK * HD;
    for (int i = threadIdx.x; i < CHUNK * HD / 8; i += 256) {
        ((uint4*)sk)[i] = ((const uint4*)(kk + base))[i];
        ((uint4*)sv)[i] = ((const uint4*)(vv + base))[i];
    }
    if (threadIdx.x < CHUNK) {
        int tg = ch * CHUNK + threadIdx.x;
        float ang = 1.5707963267948966f * (float)tg * (1.0f / (float)T_SEQ);
        cwt[threadIdx.x] = cosf(ang);
        swt[threadIdx.x] = sinf(ang);
    }
    __syncthreads();
    const int i  = threadIdx.x & 63;
    const int jg = (threadIdx.x >> 6) * 16;
    float ac[16], as[16];
    for (int jj = 0; jj < 16; ++jj) { ac[jj] = 0.f; as[jj] = 0.f; }
    for (int t = 0; t < CHUNK; ++t) {
        float kv = (float)sk[t * HD + i];
        float kc_ = kv * cwt[t];
        float ks_ = kv * swt[t];
        for (int jj = 0; jj < 16; ++jj) {
            float vj = (float)sv[t * HD + jg + jj];
            ac[jj] += kc_ * vj;
            as[jj] += ks_ * vj;
        }
    }
    bf16_t* oc = Ssc + blk * HD * HD;
    bf16_t* os = Sss + blk * HD * HD;
    for (int jj = 0; jj < 16; ++jj) {
        oc[(jg + jj) * HD + i] = (bf16_t)ac[jj];   // transposed: [e][i]
        os[(jg + jj) * HD + i] = (bf16_t)as[jj];
    }
    if (threadIdx.x < HD) {
        int ii = threadIdx.x;
        float s = 0.f;
        for (int t = 0; t < CHUNK; ++t) s += (float)sk[t * HD + ii] * cwt[t];
        zc[blk * HD + ii] = s;
    } else if (threadIdx.x < 2 * HD) {
        int ii = threadIdx.x - HD;
        float s = 0.f;
        for (int t = 0; t < CHUNK; ++t) s += (float)sk[t * HD + ii] * swt[t];
        zs[blk * HD + ii] = s;
    }
}

// ---------------------------------------------------------------------------
// K4 (R5 MFMA core + on-the-fly prefix): per-chunk output, no scan kernel.
// Each block accumulates S/z prefixes over chunks c < ch while staging.
// ---------------------------------------------------------------------------
__global__ __launch_bounds__(256) void chunk_out_kernel(
    const bf16_t* __restrict__ qq, const bf16_t* __restrict__ kk,
    const bf16_t* __restrict__ vv,
    const bf16_t* __restrict__ SscT, const bf16_t* __restrict__ SssT,
    const float* __restrict__ zc, const float* __restrict__ zs,
    bf16_t* __restrict__ Y)
{
    const int blk = blockIdx.x;
    const int bh = blk >> 4, ch = blk & 15;
    __shared__ __align__(16) bf16_t sq [CHUNK * LDA];
    __shared__ __align__(16) bf16_t sk [CHUNK * LDA];
    __shared__ __align__(16) bf16_t svT[CHUNK * LDA];
    __shared__ __align__(16) bf16_t sct[CHUNK * LDA];
    __shared__ __align__(16) bf16_t sst[CHUNK * LDA];
    __shared__ __align__(16) bf16_t sp [CHUNK * LDA];
    __shared__ float cwt[CHUNK], swt[CHUNK], cosd[CHUNK];
    __shared__ float zcl[CHUNK], zsl[CHUNK], nrm[CHUNK];

    const int base = blk * CHUNK * HD;
    // R5-proven staging: q,k row copies; V transposed in-kernel.
    for (int i = threadIdx.x; i < CHUNK * HD / 8; i += 256) {
        int row = i >> 3, g = i & 7;
        ((uint4*)(sq + row * LDA))[g]  = ((const uint4*)(qq + base))[i];
        ((uint4*)(sk + row * LDA))[g]  = ((const uint4*)(kk + base))[i];
        bf16x8 v8 = *(const bf16x8*)(vv + base + i * 8);
        int t = i >> 3, e0 = (i & 7) * 8;
        for (int j = 0; j < 8; ++j) svT[(e0 + j) * LDA + t] = v8[j];
    }
    // on-the-fly exclusive prefix of S over chunks < ch (fp32 acc -> bf16 LDS)
    {
        const int e0 = threadIdx.x * 16;            // flat elems [e0, e0+16)
        float accC[16], accS[16];
        for (int j = 0; j < 16; ++j) { accC[j] = 0.f; accS[j] = 0.f; }
        const int sb = bh * NCHUNK * HD * HD + e0;
        for (int c = 0; c < ch; ++c) {
            const bf16x8* pc = (const bf16x8*)(SscT + sb + c * HD * HD);
            const bf16x8* ps = (const bf16x8*)(SssT + sb + c * HD * HD);
            bf16x8 c0 = pc[0], c1 = pc[1], s0 = ps[0], s1 = ps[1];
            for (int j = 0; j < 8; ++j) {
                accC[j] += (float)c0[j];  accC[8 + j] += (float)c1[j];
                accS[j] += (float)s0[j];  accS[8 + j] += (float)s1[j];
            }
        }
        const int row = threadIdx.x >> 2, col = (threadIdx.x & 3) * 16;
        bf16x8 oc0, oc1, os0, os1;
        for (int j = 0; j < 8; ++j) {
            oc0[j] = (bf16_t)accC[j];  oc1[j] = (bf16_t)accC[8 + j];
            os0[j] = (bf16_t)accS[j];  os1[j] = (bf16_t)accS[8 + j];
        }
        *(bf16x8*)(sct + row * LDA + col) = oc0;
        *(bf16x8*)(sct + row * LDA + col + 8) = oc1;
        *(bf16x8*)(sst + row * LDA + col) = os0;
        *(bf16x8*)(sst + row * LDA + col + 8) = os1;
    }
    // z prefix + angle tables
    if (threadIdx.x < HD) {
        int tl = threadIdx.x;
        float s = 0.f;
        for (int c = 0; c < ch; ++c) s += zc[(bh * NCHUNK + c) * HD + tl];
        zcl[tl] = s;
        int tg = ch * CHUNK + tl;
        float angg = 1.5707963267948966f * (float)tg * (1.0f / (float)T_SEQ);
        cwt[tl] = cosf(angg);
        swt[tl] = sinf(angg);
        cosd[tl] = cosf(1.5707963267948966f * (float)tl * (1.0f / (float)T_SEQ));
    } else if (threadIdx.x < 2 * HD) {
        int i = threadIdx.x - HD;
        float s = 0.f;
        for (int c = 0; c < ch; ++c) s += zs[(bh * NCHUNK + c) * HD + i];
        zsl[i] = s;
    }
    __syncthreads();

    const int w = threadIdx.x >> 6;
    const int lane = threadIdx.x & 63;
    const int rsel = lane & 15;
    const int koff = (lane >> 4) * 8;
    const int myrow = w * 16 + rsel;

    // ---- P = q' k'^T, scale+mask, bf16 rows (wave-local) ----
    bf16x8 aq0 = *(const bf16x8*)(sq + myrow * LDA + koff);
    bf16x8 aq1 = *(const bf16x8*)(sq + myrow * LDA + koff + 32);
    for (int nt = 0; nt < 4; ++nt) {
        const int n0 = nt * 16;
        f32x4 pacc = {0.f, 0.f, 0.f, 0.f};
        bf16x8 b0 = *(const bf16x8*)(sk + (n0 + rsel) * LDA + koff);
        bf16x8 b1 = *(const bf16x8*)(sk + (n0 + rsel) * LDA + koff + 32);
        pacc = __builtin_amdgcn_mfma_f32_16x16x32_bf16(aq0, b0, pacc, 0, 0, 0);
        pacc = __builtin_amdgcn_mfma_f32_16x16x32_bf16(aq1, b1, pacc, 0, 0, 0);
        const int s = n0 + (lane & 15);
        const int tb = w * 16 + (lane >> 4) * 4;
        for (int r = 0; r < 4; ++r) {
            int t = tb + r;
            float p = (s <= t) ? pacc[r] * cosd[t - s] : 0.f;
            sp[t * LDA + s] = (bf16_t)p;
        }
    }

    // ---- nrm (lanes 0..15 of each wave; rows wave-local) ----
    if (lane < 16) {
        int row = w * 16 + lane;
        float nv = 0.f;
        const bf16x8* pr = (const bf16x8*)(sp + row * LDA);
        for (int g = 0; g < 8; ++g) {
            bf16x8 pv = pr[g];
            for (int j = 0; j < 8; ++j) nv += (float)pv[j];
        }
        float cwr = cwt[row], swr = swt[row];
        const bf16x8* qr = (const bf16x8*)(sq + row * LDA);
        for (int g = 0; g < 8; ++g) {
            bf16x8 qv = qr[g];
            for (int j = 0; j < 8; ++j)
                nv += (float)qv[j] * (cwr * zcl[g * 8 + j] + swr * zsl[g * 8 + j]);
        }
        nrm[row] = nv;
    }

    // ---- ctx = P@V + q'c@Sc + q's@Ss ----
    const float cwq = cwt[myrow], swq = swt[myrow];
    bf16x8 qc0, qc1, qs0, qs1;
    for (int j = 0; j < 8; ++j) {
        qc0[j] = (bf16_t)((float)aq0[j] * cwq);
        qc1[j] = (bf16_t)((float)aq1[j] * cwq);
        qs0[j] = (bf16_t)((float)aq0[j] * swq);
        qs1[j] = (bf16_t)((float)aq1[j] * swq);
    }
    bf16x8 ap0 = *(const bf16x8*)(sp + myrow * LDA + koff);
    bf16x8 ap1 = *(const bf16x8*)(sp + myrow * LDA + koff + 32);

    const int b = bh >> 3, h = bh & 7;
    for (int nt = 0; nt < 4; ++nt) {
        const int n0 = nt * 16;
        const bf16_t* bvp = svT + (n0 + rsel) * LDA + koff;
        const bf16_t* bcp = sct + (n0 + rsel) * LDA + koff;
        const bf16_t* bsp = sst + (n0 + rsel) * LDA + koff;
        f32x4 acc = {0.f, 0.f, 0.f, 0.f};
        acc = __builtin_amdgcn_mfma_f32_16x16x32_bf16(ap0, *(const bf16x8*)(bvp), acc, 0, 0, 0);
        acc = __builtin_amdgcn_mfma_f32_16x16x32_bf16(ap1, *(const bf16x8*)(bvp + 32), acc, 0, 0, 0);
        acc = __builtin_amdgcn_mfma_f32_16x16x32_bf16(qc0, *(const bf16x8*)(bcp), acc, 0, 0, 0);
        acc = __builtin_amdgcn_mfma_f32_16x16x32_bf16(qc1, *(const bf16x8*)(bcp + 32), acc, 0, 0, 0);
        acc = __builtin_amdgcn_mfma_f32_16x16x32_bf16(qs0, *(const bf16x8*)(bsp), acc, 0, 0, 0);
        acc = __builtin_amdgcn_mfma_f32_16x16x32_bf16(qs1, *(const bf16x8*)(bsp + 32), acc, 0, 0, 0);
        const int col = n0 + (lane & 15);
        const int tb = w * 16 + (lane >> 4) * 4;
        for (int r = 0; r < 4; ++r) {
            int row = tb + r;
            float inv = 1.0f / (nrm[row] + 1e-6f);
            int tg = ch * CHUNK + row;
            Y[((b * T_SEQ + tg) * EMB) + h * HD + col] = (bf16_t)(acc[r] * inv);
        }
    }
}

// ---------------------------------------------------------------------------
// K5: out = Y @ w_out^T + b_out, register-blocked 2x2 per wave, fp32 out.
// ---------------------------------------------------------------------------
__global__ __launch_bounds__(256) void out_gemm_kernel(
    const bf16_t* __restrict__ Yb, const bf16_t* __restrict__ W,
    const float* __restrict__ bias, float* __restrict__ out)
{
    const int w = threadIdx.x >> 6;
    const int lane = threadIdx.x & 63;
    const int rsel = lane & 15;
    const int koff = (lane >> 4) * 8;
    const int m0 = blockIdx.x * 64 + (w & 1) * 32;
    const int n0 = blockIdx.y * 64 + (w >> 1) * 32;
    f32x4 acc[2][2] = {};
    const bf16_t* Ap = Yb + (m0 + rsel) * EMB + koff;
    const bf16_t* Bp = W + (n0 + rsel) * EMB + koff;
#pragma unroll 4
    for (int k0 = 0; k0 < EMB; k0 += 32) {
        bf16x8 af[2], bfr[2];
        for (int i = 0; i < 2; ++i)
            af[i] = *(const bf16x8*)(Ap + i * 16 * EMB + k0);
        for (int j = 0; j < 2; ++j)
            bfr[j] = *(const bf16x8*)(Bp + j * 16 * EMB + k0);
        for (int i = 0; i < 2; ++i)
            for (int j = 0; j < 2; ++j)
                acc[i][j] = __builtin_amdgcn_mfma_f32_16x16x32_bf16(
                    af[i], bfr[j], acc[i][j], 0, 0, 0);
    }
    for (int j = 0; j < 2; ++j) {
        const int n = n0 + j * 16 + rsel;
        const float bn = bias[n];
        for (int i = 0; i < 2; ++i) {
            const int mb = m0 + i * 16 + (lane >> 4) * 4;
            for (int r = 0; r < 4; ++r)
                out[(mb + r) * EMB + n] = acc[i][j][r] + bn;
        }
    }
}

extern "C" void kernel_launch(void* const* d_in, const int* in_sizes, int n_in,
                              void* d_out, int out_size, void* d_ws, size_t ws_size,
                              hipStream_t stream) {
    const float* x     = (const float*)d_in[0];
    const float* w_qkv = (const float*)d_in[1];
    const float* b_qkv = (const float*)d_in[2];
    const float* w_out = (const float*)d_in[3];
    const float* b_out = (const float*)d_in[4];
    float* out = (float*)d_out;

    char* w = (char*)d_ws;
    const size_t N_X   = (size_t)BATCH * T_SEQ * EMB;
    const size_t N_WQ  = (size_t)3 * EMB * EMB;
    const size_t N_WO  = (size_t)EMB * EMB;
    bf16_t* xb   = (bf16_t*)w;                 w += N_X  * sizeof(bf16_t);
    bf16_t* wqb  = (bf16_t*)w;                 w += N_WQ * sizeof(bf16_t);
    bf16_t* wob  = (bf16_t*)w;                 w += N_WO * sizeof(bf16_t);
    const size_t SZ_BHTD = (size_t)NBH * T_SEQ * HD * sizeof(bf16_t);
    bf16_t* qq = (bf16_t*)w;                   w += SZ_BHTD;
    bf16_t* kk = (bf16_t*)w;                   w += SZ_BHTD;
    bf16_t* vv = (bf16_t*)w;                   w += SZ_BHTD;
    bf16_t* Y  = (bf16_t*)w;                   w += SZ_BHTD;
    bf16_t* SscT = (bf16_t*)w;                 w += (size_t)NBLK * HD * HD * sizeof(bf16_t);
    bf16_t* SssT = (bf16_t*)w;                 w += (size_t)NBLK * HD * HD * sizeof(bf16_t);
    float* zc = (float*)w;                     w += (size_t)NBLK * HD * sizeof(float);
    float* zs = (float*)w;

    cvt3_kernel<<<2048, 256, 0, stream>>>(x, w_qkv, w_out, xb, wqb, wob);
    qkv_gemm_kernel<<<dim3(2048 / 128, 1536 / 128), 256, 0, stream>>>(
        xb, wqb, b_qkv, qq, kk, vv);
    chunk_sum_kernel<<<NBLK, 256, 0, stream>>>(kk, vv, SscT, SssT, zc, zs);
    chunk_out_kernel<<<NBLK, 256, 0, stream>>>(qq, kk, vv, SscT, SssT, zc, zs, Y);
    out_gemm_kernel<<<dim3(2048 / 64, 512 / 64), 256, 0, stream>>>(
        Y, wob, b_out, out);
}